// Round 12
// baseline (795.252 us; speedup 1.0000x reference)
//
#include <hip/hip_runtime.h>

typedef __attribute__((ext_vector_type(8))) short bf16x8;   // 8 bf16 = 4 VGPRs
typedef __attribute__((ext_vector_type(4))) float f32x4;    // MFMA acc

#define NBKT 512          // padded bucket array (real buckets = ceil(N/128) = 391)

// fp32 -> bf16 round-to-nearest-even
__device__ __forceinline__ unsigned short f2bf(float f) {
  unsigned int u = __float_as_uint(f);
  return (unsigned short)((u + 0x7FFFu + ((u >> 16) & 1u)) >> 16);
}

// ---------------- MFMA bf16 GEMM: out[M,128] = act(A[M,K] @ W[K,128] + bias) ------
// B pre-transposed bf16: BT[128][K]. Block = 4 waves, 64 rows (16/wave).
// Fragment layout (m89/m91-verified): A/B lane l -> elem row/col=l&15, k=(l>>4)*8+i;
// C/D lane l -> col=l&15, row=(l>>4)*4+j.
template<int K, bool RELU, bool OBF16, bool A_F32>
__global__ __launch_bounds__(256) void gemm_mfma(const void* __restrict__ Av,
                                                 const unsigned short* __restrict__ BT,
                                                 const float* __restrict__ bias,
                                                 void* __restrict__ outv, int M) {
  const int t = threadIdx.x;
  const int w = t >> 6;
  const int l = t & 63;
  const int r0 = blockIdx.x * 64 + w * 16;
  const int arow = l & 15;
  const int kq = l >> 4;

  int rowA = r0 + arow; if (rowA >= M) rowA = M - 1;

  f32x4 acc[8];
#pragma unroll
  for (int n = 0; n < 8; ++n) acc[n] = (f32x4){0.f, 0.f, 0.f, 0.f};

#pragma unroll
  for (int ks = 0; ks < K / 32; ++ks) {
    bf16x8 a;
    if (A_F32) {
      const float* ap = (const float*)Av + (size_t)rowA * K + ks * 32 + kq * 8;
      float4 f0 = *(const float4*)ap;
      float4 f1 = *(const float4*)(ap + 4);
      a[0] = (short)f2bf(f0.x); a[1] = (short)f2bf(f0.y);
      a[2] = (short)f2bf(f0.z); a[3] = (short)f2bf(f0.w);
      a[4] = (short)f2bf(f1.x); a[5] = (short)f2bf(f1.y);
      a[6] = (short)f2bf(f1.z); a[7] = (short)f2bf(f1.w);
    } else {
      a = *(const bf16x8*)((const unsigned short*)Av + (size_t)rowA * K + ks * 32 + kq * 8);
    }
#pragma unroll
    for (int n = 0; n < 8; ++n) {
      bf16x8 b = *(const bf16x8*)(BT + (size_t)(n * 16 + arow) * K + ks * 32 + kq * 8);
      acc[n] = __builtin_amdgcn_mfma_f32_16x16x32_bf16(a, b, acc[n], 0, 0, 0);
    }
  }

#pragma unroll
  for (int n = 0; n < 8; ++n) {
    int col = n * 16 + arow;
    float bv = bias[col];
#pragma unroll
    for (int j = 0; j < 4; ++j) {
      int row = r0 + kq * 4 + j;
      if (row < M) {
        float v = acc[n][j] + bv;
        if (RELU) v = fmaxf(v, 0.f);
        if (OBF16) ((unsigned short*)outv)[(size_t)row * 128 + col] = f2bf(v);
        else       ((float*)outv)[(size_t)row * 128 + col] = v;
      }
    }
  }
}

// ---------------- W transpose + bf16 convert (tiny, once per call) ----------------
__global__ __launch_bounds__(256) void prep_wt(const float* __restrict__ Wp,
                                               const float* __restrict__ Wa,
                                               unsigned short* __restrict__ WpT,
                                               unsigned short* __restrict__ WaT) {
  int i = blockIdx.x * 256 + threadIdx.x;
  if (i < 128 * 256) {                 // WpT[128][256] <- Wp[256][128]
    int c = i >> 8, k = i & 255;
    WpT[i] = f2bf(Wp[k * 128 + c]);
  } else if (i < 128 * 256 + 128 * 128) {
    int j = i - 128 * 256;             // WaT[128][128] <- Wa[128][128]
    int c = j >> 7, k = j & 127;
    WaT[j] = f2bf(Wa[k * 128 + c]);
  }
}

// ---------------- Pass A1: per-bucket edge counts (LDS-aggregated) ----------------
__global__ __launch_bounds__(256) void bucket_count(const int* __restrict__ ei,
                                                    int* __restrict__ bcnt, int E) {
  __shared__ int c[NBKT];
  for (int i = threadIdx.x; i < NBKT; i += 256) c[i] = 0;
  __syncthreads();
  for (int e = blockIdx.x * 256 + threadIdx.x; e < E; e += gridDim.x * 256)
    atomicAdd(&c[ei[E + e] >> 7], 1);
  __syncthreads();
  for (int i = threadIdx.x; i < NBKT; i += 256)
    if (c[i]) atomicAdd(&bcnt[i], c[i]);
}

// ---------------- Pass A2: exclusive scan of 512 bucket counts ----------------
__global__ __launch_bounds__(512) void scan_buckets(const int* __restrict__ bcnt,
                                                    int* __restrict__ bbase,
                                                    int* __restrict__ bcur, int E) {
  __shared__ int s[512];
  int t = threadIdx.x;
  int v = bcnt[t];
  s[t] = v;
  __syncthreads();
#pragma unroll
  for (int o = 1; o < 512; o <<= 1) {
    int tv = (t >= o) ? s[t - o] : 0;
    __syncthreads();
    s[t] += tv;
    __syncthreads();
  }
  int excl = s[t] - v;
  bbase[t] = excl;
  bcur[t] = excl;
  if (t == 511) bbase[512] = E;
}

// ---------------- Pass A3: bin edges (block-aggregated reservation) ----------------
// Chunk of 4096 edges per block held in registers; per-bucket LDS rank; one global
// atomicAdd per (block,bucket) reserves a contiguous run -> coalesced run writes.
// binned[j] = { dstLocal (0..127), (src<<16)|bf16(w) }
__global__ __launch_bounds__(256) void bin_fill(const int* __restrict__ ei,
                                                const float* __restrict__ ew,
                                                int* __restrict__ bcur,
                                                uint2* __restrict__ binned, int E) {
  __shared__ int cnt[NBKT];
  __shared__ int base[NBKT];
  const int t = threadIdx.x;
  const int c0 = blockIdx.x * 4096;
  for (int i = t; i < NBKT; i += 256) cnt[i] = 0;
  __syncthreads();

  int dst[16]; unsigned pk[16]; int rnk[16];
#pragma unroll
  for (int i = 0; i < 16; ++i) {
    int e = c0 + i * 256 + t;
    if (e < E) {
      int d = ei[E + e];
      dst[i] = d;
      pk[i] = ((unsigned)ei[e] << 16) | (unsigned)f2bf(ew[e]);
      rnk[i] = atomicAdd(&cnt[d >> 7], 1);
    } else dst[i] = -1;
  }
  __syncthreads();
  for (int i = t; i < NBKT; i += 256) {
    int c = cnt[i];
    base[i] = c ? atomicAdd(&bcur[i], c) : 0;
  }
  __syncthreads();
#pragma unroll
  for (int i = 0; i < 16; ++i) {
    if (dst[i] >= 0) {
      int b = dst[i] >> 7;
      binned[base[b] + rnk[i]] = make_uint2((unsigned)(dst[i] & 127), pk[i]);
    }
  }
}

// ---------------- Pass B: fused bucket gather-accumulate ----------------
// One block per bucket (128 dsts). 64KB LDS fp32 accumulator; 8 waves process
// edges in batches of 4 (headers then gathers in flight), ds_add_f32 accumulate,
// one coalesced bf16 writeback. No global scatter at all.
__global__ __launch_bounds__(512) void bucket_gather(const unsigned short* __restrict__ xb,
                                                     const uint2* __restrict__ binned,
                                                     const int* __restrict__ bbase,
                                                     unsigned short* __restrict__ aggb,
                                                     int N) {
  __shared__ float acc[128 * 128];    // 64 KB
  const int b = blockIdx.x;
  const int t = threadIdx.x;
  for (int i = t; i < 128 * 32; i += 512)
    ((float4*)acc)[i] = make_float4(0.f, 0.f, 0.f, 0.f);
  __syncthreads();

  const int w = t >> 6, l = t & 63;
  const int cc0 = l * 2;
  const int js = bbase[b], je = bbase[b + 1];

  for (int j0 = js + w * 4; j0 < je; j0 += 32) {
    uint2 h[4];
#pragma unroll
    for (int q = 0; q < 4; ++q) {
      int j = j0 + q;
      h[q] = (j < je) ? binned[j] : make_uint2(0u, 0u);  // w=bf16(0) -> adds 0
    }
    unsigned v[4];
#pragma unroll
    for (int q = 0; q < 4; ++q)
      v[q] = *(const unsigned*)(xb + (size_t)(h[q].y >> 16) * 128 + cc0);
#pragma unroll
    for (int q = 0; q < 4; ++q) {
      float wgt = __uint_as_float(h[q].y << 16);
      int dl = (int)h[q].x;
      atomicAdd(&acc[dl * 128 + cc0],     wgt * __uint_as_float(v[q] << 16));
      atomicAdd(&acc[dl * 128 + cc0 + 1], wgt * __uint_as_float(v[q] & 0xFFFF0000u));
    }
  }
  __syncthreads();

  const int d0 = b * 128;
  for (int i = t; i < 128 * 64; i += 512) {     // 128 rows x 64 packed uints
    int r = i >> 6, cc = (i & 63) * 2;
    int dst = d0 + r;
    if (dst < N) {
      unsigned p = ((unsigned)f2bf(acc[r * 128 + cc + 1]) << 16) |
                   (unsigned)f2bf(acc[r * 128 + cc]);
      *(unsigned*)(aggb + (size_t)dst * 128 + cc) = p;
    }
  }
}

extern "C" void kernel_launch(void* const* d_in, const int* in_sizes, int n_in,
                              void* d_out, int out_size, void* d_ws, size_t ws_size,
                              hipStream_t stream) {
  const float* features = (const float*)d_in[0];
  const int* ei = (const int*)d_in[1];   // [2, E] int32
  const float* ew = (const float*)d_in[2];
  const float* Wp = (const float*)d_in[3];
  const float* bp = (const float*)d_in[4];
  const float* Wa = (const float*)d_in[5];
  const float* ba = (const float*)d_in[6];

  const int N = in_sizes[0] / 256;  // 50000
  const int E = in_sizes[1] / 2;    // 800000

  float* out = (float*)d_out;

  // Workspace layout (256B-aligned), ~32.2 MB:
  char* ws = (char*)d_ws;
  size_t o = 0;
  unsigned short* xb   = (unsigned short*)(ws + o); o += (size_t)N * 128 * 2;  // 12.8 MB
  o = (o + 255) & ~(size_t)255;
  unsigned short* aggb = (unsigned short*)(ws + o); o += (size_t)N * 128 * 2;  // 12.8 MB
  o = (o + 255) & ~(size_t)255;
  uint2* binned = (uint2*)(ws + o); o += (size_t)E * 8;                        // 6.4 MB
  o = (o + 255) & ~(size_t)255;
  int* bcnt  = (int*)(ws + o); o += NBKT * 4;
  o = (o + 255) & ~(size_t)255;
  int* bbase = (int*)(ws + o); o += (NBKT + 1) * 4;
  o = (o + 255) & ~(size_t)255;
  int* bcur  = (int*)(ws + o); o += NBKT * 4;
  o = (o + 255) & ~(size_t)255;
  unsigned short* WpT = (unsigned short*)(ws + o); o += (size_t)128 * 256 * 2; // 64 KB
  o = (o + 255) & ~(size_t)255;
  unsigned short* WaT = (unsigned short*)(ws + o); o += (size_t)128 * 128 * 2; // 32 KB

  const int nbkt_real = (N + 127) / 128;        // 391
  const int nchunks = (E + 4095) / 4096;        // 196
  const int gemm_blocks = (N + 63) / 64;

  // bucket counters zeroed every call (ws never re-poisoned between replays).
  hipMemsetAsync(bcnt, 0, NBKT * sizeof(int), stream);

  // 0) W^T bf16 prep (tiny)
  prep_wt<<<(128 * 256 + 128 * 128 + 255) / 256, 256, 0, stream>>>(Wp, Wa, WpT, WaT);

  // 1) xb = bf16(features @ W_proj + b_proj)
  gemm_mfma<256, false, true, true><<<gemm_blocks, 256, 0, stream>>>(features, WpT, bp, xb, N);

  // 2) two-level binning by dst bucket (dst>>7)
  bucket_count<<<256, 256, 0, stream>>>(ei, bcnt, E);
  scan_buckets<<<1, 512, 0, stream>>>(bcnt, bbase, bcur, E);
  bin_fill<<<nchunks, 256, 0, stream>>>(ei, ew, bcur, binned, E);

  // 3) fused gather-accumulate per bucket (LDS fp32 acc, no global scatter)
  bucket_gather<<<nbkt_real, 512, 0, stream>>>(xb, binned, bbase, aggb, N);

  // 4) out = relu(aggb @ W_agg + b_agg)
  gemm_mfma<128, true, false, false><<<gemm_blocks, 256, 0, stream>>>(aggb, WaT, ba, out, N);
}

// Round 13
// 156.570 us; speedup vs baseline: 5.0792x; 5.0792x over previous
//
#include <hip/hip_runtime.h>

typedef __attribute__((ext_vector_type(8))) short bf16x8;   // 8 bf16 = 4 VGPRs
typedef __attribute__((ext_vector_type(4))) float f32x4;    // MFMA acc

#define NBKT 512          // padded bucket array (real buckets = ceil(N/128) = 391)
#define CHUNK 2048        // entries per sort pass in bucket_sort_gather

// fp32 -> bf16 round-to-nearest-even
__device__ __forceinline__ unsigned short f2bf(float f) {
  unsigned int u = __float_as_uint(f);
  return (unsigned short)((u + 0x7FFFu + ((u >> 16) & 1u)) >> 16);
}

// ---------------- MFMA bf16 GEMM: out[M,128] = act(A[M,K] @ W[K,128] + bias) ------
// B pre-transposed bf16: BT[128][K]. Block = 4 waves, 64 rows (16/wave).
// Fragment layout (m89/m91-verified): A/B lane l -> elem row/col=l&15, k=(l>>4)*8+i;
// C/D lane l -> col=l&15, row=(l>>4)*4+j.
template<int K, bool RELU, bool OBF16, bool A_F32>
__global__ __launch_bounds__(256) void gemm_mfma(const void* __restrict__ Av,
                                                 const unsigned short* __restrict__ BT,
                                                 const float* __restrict__ bias,
                                                 void* __restrict__ outv, int M) {
  const int t = threadIdx.x;
  const int w = t >> 6;
  const int l = t & 63;
  const int r0 = blockIdx.x * 64 + w * 16;
  const int arow = l & 15;
  const int kq = l >> 4;

  int rowA = r0 + arow; if (rowA >= M) rowA = M - 1;

  f32x4 acc[8];
#pragma unroll
  for (int n = 0; n < 8; ++n) acc[n] = (f32x4){0.f, 0.f, 0.f, 0.f};

#pragma unroll
  for (int ks = 0; ks < K / 32; ++ks) {
    bf16x8 a;
    if (A_F32) {
      const float* ap = (const float*)Av + (size_t)rowA * K + ks * 32 + kq * 8;
      float4 f0 = *(const float4*)ap;
      float4 f1 = *(const float4*)(ap + 4);
      a[0] = (short)f2bf(f0.x); a[1] = (short)f2bf(f0.y);
      a[2] = (short)f2bf(f0.z); a[3] = (short)f2bf(f0.w);
      a[4] = (short)f2bf(f1.x); a[5] = (short)f2bf(f1.y);
      a[6] = (short)f2bf(f1.z); a[7] = (short)f2bf(f1.w);
    } else {
      a = *(const bf16x8*)((const unsigned short*)Av + (size_t)rowA * K + ks * 32 + kq * 8);
    }
#pragma unroll
    for (int n = 0; n < 8; ++n) {
      bf16x8 b = *(const bf16x8*)(BT + (size_t)(n * 16 + arow) * K + ks * 32 + kq * 8);
      acc[n] = __builtin_amdgcn_mfma_f32_16x16x32_bf16(a, b, acc[n], 0, 0, 0);
    }
  }

#pragma unroll
  for (int n = 0; n < 8; ++n) {
    int col = n * 16 + arow;
    float bv = bias[col];
#pragma unroll
    for (int j = 0; j < 4; ++j) {
      int row = r0 + kq * 4 + j;
      if (row < M) {
        float v = acc[n][j] + bv;
        if (RELU) v = fmaxf(v, 0.f);
        if (OBF16) ((unsigned short*)outv)[(size_t)row * 128 + col] = f2bf(v);
        else       ((float*)outv)[(size_t)row * 128 + col] = v;
      }
    }
  }
}

// ---------------- W transpose + bf16 convert (tiny, once per call) ----------------
__global__ __launch_bounds__(256) void prep_wt(const float* __restrict__ Wp,
                                               const float* __restrict__ Wa,
                                               unsigned short* __restrict__ WpT,
                                               unsigned short* __restrict__ WaT) {
  int i = blockIdx.x * 256 + threadIdx.x;
  if (i < 128 * 256) {                 // WpT[128][256] <- Wp[256][128]
    int c = i >> 8, k = i & 255;
    WpT[i] = f2bf(Wp[k * 128 + c]);
  } else if (i < 128 * 256 + 128 * 128) {
    int j = i - 128 * 256;             // WaT[128][128] <- Wa[128][128]
    int c = j >> 7, k = j & 127;
    WaT[j] = f2bf(Wa[k * 128 + c]);
  }
}

// ---------------- Pass A1: per-bucket edge counts (LDS-aggregated) ----------------
__global__ __launch_bounds__(256) void bucket_count(const int* __restrict__ ei,
                                                    int* __restrict__ bcnt, int E) {
  __shared__ int c[NBKT];
  for (int i = threadIdx.x; i < NBKT; i += 256) c[i] = 0;
  __syncthreads();
  for (int e = blockIdx.x * 256 + threadIdx.x; e < E; e += gridDim.x * 256)
    atomicAdd(&c[ei[E + e] >> 7], 1);
  __syncthreads();
  for (int i = threadIdx.x; i < NBKT; i += 256)
    if (c[i]) atomicAdd(&bcnt[i], c[i]);
}

// ---------------- Pass A2: exclusive scan of 512 bucket counts ----------------
__global__ __launch_bounds__(512) void scan_buckets(const int* __restrict__ bcnt,
                                                    int* __restrict__ bbase,
                                                    int* __restrict__ bcur, int E) {
  __shared__ int s[512];
  int t = threadIdx.x;
  int v = bcnt[t];
  s[t] = v;
  __syncthreads();
#pragma unroll
  for (int o = 1; o < 512; o <<= 1) {
    int tv = (t >= o) ? s[t - o] : 0;
    __syncthreads();
    s[t] += tv;
    __syncthreads();
  }
  int excl = s[t] - v;
  bbase[t] = excl;
  bcur[t] = excl;
  if (t == 511) bbase[512] = E;
}

// ---------------- Pass A3: bin edges (block-aggregated reservation) ----------------
// Chunk of 4096 edges per block held in registers; per-bucket LDS rank; one global
// atomicAdd per (block,bucket) reserves a contiguous run -> coalesced run writes.
// binned[j] = { dstLocal (0..127), (src<<16)|bf16(w) }
__global__ __launch_bounds__(256) void bin_fill(const int* __restrict__ ei,
                                                const float* __restrict__ ew,
                                                int* __restrict__ bcur,
                                                uint2* __restrict__ binned, int E) {
  __shared__ int cnt[NBKT];
  __shared__ int base[NBKT];
  const int t = threadIdx.x;
  const int c0 = blockIdx.x * 4096;
  for (int i = t; i < NBKT; i += 256) cnt[i] = 0;
  __syncthreads();

  int dst[16]; unsigned pk[16]; int rnk[16];
#pragma unroll
  for (int i = 0; i < 16; ++i) {
    int e = c0 + i * 256 + t;
    if (e < E) {
      int d = ei[E + e];
      dst[i] = d;
      pk[i] = ((unsigned)ei[e] << 16) | (unsigned)f2bf(ew[e]);
      rnk[i] = atomicAdd(&cnt[d >> 7], 1);
    } else dst[i] = -1;
  }
  __syncthreads();
  for (int i = t; i < NBKT; i += 256) {
    int c = cnt[i];
    base[i] = c ? atomicAdd(&bcur[i], c) : 0;
  }
  __syncthreads();
#pragma unroll
  for (int i = 0; i < 16; ++i) {
    if (dst[i] >= 0) {
      int b = dst[i] >> 7;
      binned[base[b] + rnk[i]] = make_uint2((unsigned)(dst[i] & 127), pk[i]);
    }
  }
}

// ---------------- Pass B: counting-sort + register-accumulate gather ----------------
// One block (512 thr) per 128-dst bucket. Chunks of <=2048 entries: int-LDS rank,
// scan, scatter to dst-sorted LDS; then wave w accumulates dsts [w*16, w*16+16) in
// float2 registers with 4-edge-batched global gathers. NO float atomics anywhere.
__global__ __launch_bounds__(512) void bucket_sort_gather(
    const unsigned short* __restrict__ xb,
    const uint2* __restrict__ binned,
    const int* __restrict__ bbase,
    unsigned short* __restrict__ aggb, int N) {
  __shared__ unsigned sorted[CHUNK];   // 8 KB, (src<<16)|bf16w; dl implicit by segment
  __shared__ int cnt[128];
  __shared__ int scn[128];
  __shared__ int start[128];

  const int b = blockIdx.x;
  const int t = threadIdx.x;
  const int w = t >> 6, l = t & 63;
  const int cc0 = l * 2;
  const int js = bbase[b], je = bbase[b + 1];

  float2 acc[16];
#pragma unroll
  for (int i = 0; i < 16; ++i) acc[i] = make_float2(0.f, 0.f);

  for (int cs = js; cs < je; cs += CHUNK) {
    const int n = min(CHUNK, je - cs);
    if (t < 128) cnt[t] = 0;
    __syncthreads();

    int dl[4]; unsigned pk[4]; int rk[4];
#pragma unroll
    for (int q = 0; q < 4; ++q) {
      int i = q * 512 + t;
      if (i < n) {
        uint2 e = binned[cs + i];
        dl[q] = (int)e.x; pk[q] = e.y;
        rk[q] = atomicAdd(&cnt[dl[q]], 1);   // native int LDS atomic
      } else dl[q] = -1;
    }
    __syncthreads();

    // exclusive scan of cnt[128] (Hillis-Steele, whole block syncs)
    if (t < 128) scn[t] = cnt[t];
    __syncthreads();
#pragma unroll
    for (int o = 1; o < 128; o <<= 1) {
      int v = 0;
      if (t < 128 && t >= o) v = scn[t - o];
      __syncthreads();
      if (t < 128) scn[t] += v;
      __syncthreads();
    }
    if (t < 128) start[t] = scn[t] - cnt[t];
    __syncthreads();

#pragma unroll
    for (int q = 0; q < 4; ++q)
      if (dl[q] >= 0) sorted[start[dl[q]] + rk[q]] = pk[q];
    __syncthreads();

    // accumulate: wave w owns dl in [w*16, w*16+16)
    for (int i = 0; i < 16; ++i) {
      const int d = w * 16 + i;
      const int s0 = start[d], c = cnt[d];   // wave-uniform LDS broadcast
      int j = 0;
      for (; j + 4 <= c; j += 4) {
        unsigned p0 = sorted[s0 + j],     p1 = sorted[s0 + j + 1];
        unsigned p2 = sorted[s0 + j + 2], p3 = sorted[s0 + j + 3];
        unsigned v0 = *(const unsigned*)(xb + (size_t)(p0 >> 16) * 128 + cc0);
        unsigned v1 = *(const unsigned*)(xb + (size_t)(p1 >> 16) * 128 + cc0);
        unsigned v2 = *(const unsigned*)(xb + (size_t)(p2 >> 16) * 128 + cc0);
        unsigned v3 = *(const unsigned*)(xb + (size_t)(p3 >> 16) * 128 + cc0);
        float w0 = __uint_as_float(p0 << 16), w1 = __uint_as_float(p1 << 16);
        float w2 = __uint_as_float(p2 << 16), w3 = __uint_as_float(p3 << 16);
        acc[i].x = fmaf(w0, __uint_as_float(v0 << 16), acc[i].x);
        acc[i].y = fmaf(w0, __uint_as_float(v0 & 0xFFFF0000u), acc[i].y);
        acc[i].x = fmaf(w1, __uint_as_float(v1 << 16), acc[i].x);
        acc[i].y = fmaf(w1, __uint_as_float(v1 & 0xFFFF0000u), acc[i].y);
        acc[i].x = fmaf(w2, __uint_as_float(v2 << 16), acc[i].x);
        acc[i].y = fmaf(w2, __uint_as_float(v2 & 0xFFFF0000u), acc[i].y);
        acc[i].x = fmaf(w3, __uint_as_float(v3 << 16), acc[i].x);
        acc[i].y = fmaf(w3, __uint_as_float(v3 & 0xFFFF0000u), acc[i].y);
      }
      for (; j < c; ++j) {
        unsigned p = sorted[s0 + j];
        unsigned v = *(const unsigned*)(xb + (size_t)(p >> 16) * 128 + cc0);
        float wg = __uint_as_float(p << 16);
        acc[i].x = fmaf(wg, __uint_as_float(v << 16), acc[i].x);
        acc[i].y = fmaf(wg, __uint_as_float(v & 0xFFFF0000u), acc[i].y);
      }
    }
    __syncthreads();   // LDS reused next chunk
  }

  // writeback: wave w writes its 16 dst rows (coalesced 256B per row)
  const int d0 = b * 128;
#pragma unroll
  for (int i = 0; i < 16; ++i) {
    int dst = d0 + w * 16 + i;
    if (dst < N) {
      unsigned p = ((unsigned)f2bf(acc[i].y) << 16) | (unsigned)f2bf(acc[i].x);
      *(unsigned*)(aggb + (size_t)dst * 128 + cc0) = p;
    }
  }
}

extern "C" void kernel_launch(void* const* d_in, const int* in_sizes, int n_in,
                              void* d_out, int out_size, void* d_ws, size_t ws_size,
                              hipStream_t stream) {
  const float* features = (const float*)d_in[0];
  const int* ei = (const int*)d_in[1];   // [2, E] int32
  const float* ew = (const float*)d_in[2];
  const float* Wp = (const float*)d_in[3];
  const float* bp = (const float*)d_in[4];
  const float* Wa = (const float*)d_in[5];
  const float* ba = (const float*)d_in[6];

  const int N = in_sizes[0] / 256;  // 50000
  const int E = in_sizes[1] / 2;    // 800000

  float* out = (float*)d_out;

  // Workspace layout (256B-aligned), ~32.2 MB:
  char* ws = (char*)d_ws;
  size_t o = 0;
  unsigned short* xb   = (unsigned short*)(ws + o); o += (size_t)N * 128 * 2;  // 12.8 MB
  o = (o + 255) & ~(size_t)255;
  unsigned short* aggb = (unsigned short*)(ws + o); o += (size_t)N * 128 * 2;  // 12.8 MB
  o = (o + 255) & ~(size_t)255;
  uint2* binned = (uint2*)(ws + o); o += (size_t)E * 8;                        // 6.4 MB
  o = (o + 255) & ~(size_t)255;
  int* bcnt  = (int*)(ws + o); o += NBKT * 4;
  o = (o + 255) & ~(size_t)255;
  int* bbase = (int*)(ws + o); o += (NBKT + 1) * 4;
  o = (o + 255) & ~(size_t)255;
  int* bcur  = (int*)(ws + o); o += NBKT * 4;
  o = (o + 255) & ~(size_t)255;
  unsigned short* WpT = (unsigned short*)(ws + o); o += (size_t)128 * 256 * 2; // 64 KB
  o = (o + 255) & ~(size_t)255;
  unsigned short* WaT = (unsigned short*)(ws + o); o += (size_t)128 * 128 * 2; // 32 KB

  const int nbkt_real = (N + 127) / 128;        // 391
  const int nchunks = (E + 4095) / 4096;        // 196
  const int gemm_blocks = (N + 63) / 64;

  // bucket counters zeroed every call (ws never re-poisoned between replays).
  hipMemsetAsync(bcnt, 0, NBKT * sizeof(int), stream);

  // 0) W^T bf16 prep (tiny)
  prep_wt<<<(128 * 256 + 128 * 128 + 255) / 256, 256, 0, stream>>>(Wp, Wa, WpT, WaT);

  // 1) xb = bf16(features @ W_proj + b_proj)
  gemm_mfma<256, false, true, true><<<gemm_blocks, 256, 0, stream>>>(features, WpT, bp, xb, N);

  // 2) two-level binning by dst bucket (dst>>7)
  bucket_count<<<256, 256, 0, stream>>>(ei, bcnt, E);
  scan_buckets<<<1, 512, 0, stream>>>(bcnt, bbase, bcur, E);
  bin_fill<<<nchunks, 256, 0, stream>>>(ei, ew, bcur, binned, E);

  // 3) per-bucket counting-sort + register-accumulated gather (no float atomics)
  bucket_sort_gather<<<nbkt_real, 512, 0, stream>>>(xb, binned, bbase, aggb, N);

  // 4) out = relu(aggb @ W_agg + b_agg)
  gemm_mfma<128, true, false, false><<<gemm_blocks, 256, 0, stream>>>(aggb, WaT, ba, out, N);
}

// Round 14
// 150.075 us; speedup vs baseline: 5.2990x; 1.0433x over previous
//
#include <hip/hip_runtime.h>

typedef __attribute__((ext_vector_type(8))) short bf16x8;   // 8 bf16 = 4 VGPRs
typedef __attribute__((ext_vector_type(4))) float f32x4;    // MFMA acc

#define NBKT 1024         // padded bucket array (real buckets = ceil(N/64) = 782)
#define BDST 64           // dsts per bucket
#define CHUNK 2048        // entries per sort pass in bucket_sort_gather

// fp32 -> bf16 round-to-nearest-even
__device__ __forceinline__ unsigned short f2bf(float f) {
  unsigned int u = __float_as_uint(f);
  return (unsigned short)((u + 0x7FFFu + ((u >> 16) & 1u)) >> 16);
}

// ---------------- MFMA bf16 GEMM: out[M,128] = act(A[M,K] @ W[K,128] + bias) ------
// B pre-transposed bf16: BT[128][K]. Block = 4 waves, 64 rows (16/wave).
// Fragment layout (m89/m91-verified): A/B lane l -> elem row/col=l&15, k=(l>>4)*8+i;
// C/D lane l -> col=l&15, row=(l>>4)*4+j.
template<int K, bool RELU, bool OBF16, bool A_F32>
__global__ __launch_bounds__(256) void gemm_mfma(const void* __restrict__ Av,
                                                 const unsigned short* __restrict__ BT,
                                                 const float* __restrict__ bias,
                                                 void* __restrict__ outv, int M) {
  const int t = threadIdx.x;
  const int w = t >> 6;
  const int l = t & 63;
  const int r0 = blockIdx.x * 64 + w * 16;
  const int arow = l & 15;
  const int kq = l >> 4;

  int rowA = r0 + arow; if (rowA >= M) rowA = M - 1;

  f32x4 acc[8];
#pragma unroll
  for (int n = 0; n < 8; ++n) acc[n] = (f32x4){0.f, 0.f, 0.f, 0.f};

#pragma unroll
  for (int ks = 0; ks < K / 32; ++ks) {
    bf16x8 a;
    if (A_F32) {
      const float* ap = (const float*)Av + (size_t)rowA * K + ks * 32 + kq * 8;
      float4 f0 = *(const float4*)ap;
      float4 f1 = *(const float4*)(ap + 4);
      a[0] = (short)f2bf(f0.x); a[1] = (short)f2bf(f0.y);
      a[2] = (short)f2bf(f0.z); a[3] = (short)f2bf(f0.w);
      a[4] = (short)f2bf(f1.x); a[5] = (short)f2bf(f1.y);
      a[6] = (short)f2bf(f1.z); a[7] = (short)f2bf(f1.w);
    } else {
      a = *(const bf16x8*)((const unsigned short*)Av + (size_t)rowA * K + ks * 32 + kq * 8);
    }
#pragma unroll
    for (int n = 0; n < 8; ++n) {
      bf16x8 b = *(const bf16x8*)(BT + (size_t)(n * 16 + arow) * K + ks * 32 + kq * 8);
      acc[n] = __builtin_amdgcn_mfma_f32_16x16x32_bf16(a, b, acc[n], 0, 0, 0);
    }
  }

#pragma unroll
  for (int n = 0; n < 8; ++n) {
    int col = n * 16 + arow;
    float bv = bias[col];
#pragma unroll
    for (int j = 0; j < 4; ++j) {
      int row = r0 + kq * 4 + j;
      if (row < M) {
        float v = acc[n][j] + bv;
        if (RELU) v = fmaxf(v, 0.f);
        if (OBF16) ((unsigned short*)outv)[(size_t)row * 128 + col] = f2bf(v);
        else       ((float*)outv)[(size_t)row * 128 + col] = v;
      }
    }
  }
}

// ---------------- W transpose + bf16 convert (tiny, once per call) ----------------
__global__ __launch_bounds__(256) void prep_wt(const float* __restrict__ Wp,
                                               const float* __restrict__ Wa,
                                               unsigned short* __restrict__ WpT,
                                               unsigned short* __restrict__ WaT) {
  int i = blockIdx.x * 256 + threadIdx.x;
  if (i < 128 * 256) {                 // WpT[128][256] <- Wp[256][128]
    int c = i >> 8, k = i & 255;
    WpT[i] = f2bf(Wp[k * 128 + c]);
  } else if (i < 128 * 256 + 128 * 128) {
    int j = i - 128 * 256;             // WaT[128][128] <- Wa[128][128]
    int c = j >> 7, k = j & 127;
    WaT[j] = f2bf(Wa[k * 128 + c]);
  }
}

// ---------------- Pass A1: per-bucket edge counts (LDS-aggregated) ----------------
__global__ __launch_bounds__(256) void bucket_count(const int* __restrict__ ei,
                                                    int* __restrict__ bcnt, int E) {
  __shared__ int c[NBKT];
  for (int i = threadIdx.x; i < NBKT; i += 256) c[i] = 0;
  __syncthreads();
  for (int e = blockIdx.x * 256 + threadIdx.x; e < E; e += gridDim.x * 256)
    atomicAdd(&c[ei[E + e] >> 6], 1);
  __syncthreads();
  for (int i = threadIdx.x; i < NBKT; i += 256)
    if (c[i]) atomicAdd(&bcnt[i], c[i]);
}

// ---------------- Pass A2: exclusive scan of 1024 bucket counts ----------------
__global__ __launch_bounds__(1024) void scan_buckets(const int* __restrict__ bcnt,
                                                     int* __restrict__ bbase,
                                                     int* __restrict__ bcur, int E) {
  __shared__ int s[1024];
  int t = threadIdx.x;
  int v = bcnt[t];
  s[t] = v;
  __syncthreads();
#pragma unroll
  for (int o = 1; o < 1024; o <<= 1) {
    int tv = (t >= o) ? s[t - o] : 0;
    __syncthreads();
    s[t] += tv;
    __syncthreads();
  }
  int excl = s[t] - v;
  bbase[t] = excl;
  bcur[t] = excl;
  if (t == 1023) bbase[1024] = E;
}

// ---------------- Pass A3: bin edges (block-aggregated reservation) ----------------
// Chunk of 4096 edges per block held in registers; per-bucket LDS rank; one global
// atomicAdd per (block,bucket) reserves a contiguous run -> coalesced run writes.
// binned[j] = { dstLocal (0..63), (src<<16)|bf16(w) }
__global__ __launch_bounds__(256) void bin_fill(const int* __restrict__ ei,
                                                const float* __restrict__ ew,
                                                int* __restrict__ bcur,
                                                uint2* __restrict__ binned, int E) {
  __shared__ int cnt[NBKT];
  __shared__ int base[NBKT];
  const int t = threadIdx.x;
  const int c0 = blockIdx.x * 4096;
  for (int i = t; i < NBKT; i += 256) cnt[i] = 0;
  __syncthreads();

  int dst[16]; unsigned pk[16]; int rnk[16];
#pragma unroll
  for (int i = 0; i < 16; ++i) {
    int e = c0 + i * 256 + t;
    if (e < E) {
      int d = ei[E + e];
      dst[i] = d;
      pk[i] = ((unsigned)ei[e] << 16) | (unsigned)f2bf(ew[e]);
      rnk[i] = atomicAdd(&cnt[d >> 6], 1);
    } else dst[i] = -1;
  }
  __syncthreads();
  for (int i = t; i < NBKT; i += 256) {
    int c = cnt[i];
    base[i] = c ? atomicAdd(&bcur[i], c) : 0;
  }
  __syncthreads();
#pragma unroll
  for (int i = 0; i < 16; ++i) {
    if (dst[i] >= 0) {
      int b = dst[i] >> 6;
      binned[base[b] + rnk[i]] = make_uint2((unsigned)(dst[i] & 63), pk[i]);
    }
  }
}

// ---------------- Pass B: counting-sort + register-accumulate gather ----------------
// One block (512 thr) per 64-dst bucket (782 blocks -> ~3 blocks/CU for TLP).
// Chunks of <=2048 entries: int-LDS rank, scan, scatter to dst-sorted LDS; then
// wave w accumulates dsts [w*8, w*8+8) in float2 registers with 4-edge-batched
// global gathers. No float atomics anywhere.
__global__ __launch_bounds__(512) void bucket_sort_gather(
    const unsigned short* __restrict__ xb,
    const uint2* __restrict__ binned,
    const int* __restrict__ bbase,
    unsigned short* __restrict__ aggb, int N) {
  __shared__ unsigned sorted[CHUNK];   // 8 KB, (src<<16)|bf16w; dl implicit by segment
  __shared__ int cnt[BDST];
  __shared__ int scn[BDST];
  __shared__ int start[BDST];

  const int b = blockIdx.x;
  const int t = threadIdx.x;
  const int w = t >> 6, l = t & 63;
  const int cc0 = l * 2;
  const int js = bbase[b], je = bbase[b + 1];

  float2 acc[8];
#pragma unroll
  for (int i = 0; i < 8; ++i) acc[i] = make_float2(0.f, 0.f);

  for (int cs = js; cs < je; cs += CHUNK) {
    const int n = min(CHUNK, je - cs);
    if (t < BDST) cnt[t] = 0;
    __syncthreads();

    int dl[4]; unsigned pk[4]; int rk[4];
#pragma unroll
    for (int q = 0; q < 4; ++q) {
      int i = q * 512 + t;
      if (i < n) {
        uint2 e = binned[cs + i];
        dl[q] = (int)e.x; pk[q] = e.y;
        rk[q] = atomicAdd(&cnt[dl[q]], 1);   // native int LDS atomic
      } else dl[q] = -1;
    }
    __syncthreads();

    // exclusive scan of cnt[64] (Hillis-Steele, whole block syncs)
    if (t < BDST) scn[t] = cnt[t];
    __syncthreads();
#pragma unroll
    for (int o = 1; o < BDST; o <<= 1) {
      int v = 0;
      if (t < BDST && t >= o) v = scn[t - o];
      __syncthreads();
      if (t < BDST) scn[t] += v;
      __syncthreads();
    }
    if (t < BDST) start[t] = scn[t] - cnt[t];
    __syncthreads();

#pragma unroll
    for (int q = 0; q < 4; ++q)
      if (dl[q] >= 0) sorted[start[dl[q]] + rk[q]] = pk[q];
    __syncthreads();

    // accumulate: wave w owns dl in [w*8, w*8+8)
    for (int i = 0; i < 8; ++i) {
      const int d = w * 8 + i;
      const int s0 = start[d], c = cnt[d];   // wave-uniform LDS broadcast
      int j = 0;
      for (; j + 4 <= c; j += 4) {
        unsigned p0 = sorted[s0 + j],     p1 = sorted[s0 + j + 1];
        unsigned p2 = sorted[s0 + j + 2], p3 = sorted[s0 + j + 3];
        unsigned v0 = *(const unsigned*)(xb + (size_t)(p0 >> 16) * 128 + cc0);
        unsigned v1 = *(const unsigned*)(xb + (size_t)(p1 >> 16) * 128 + cc0);
        unsigned v2 = *(const unsigned*)(xb + (size_t)(p2 >> 16) * 128 + cc0);
        unsigned v3 = *(const unsigned*)(xb + (size_t)(p3 >> 16) * 128 + cc0);
        float w0 = __uint_as_float(p0 << 16), w1 = __uint_as_float(p1 << 16);
        float w2 = __uint_as_float(p2 << 16), w3 = __uint_as_float(p3 << 16);
        acc[i].x = fmaf(w0, __uint_as_float(v0 << 16), acc[i].x);
        acc[i].y = fmaf(w0, __uint_as_float(v0 & 0xFFFF0000u), acc[i].y);
        acc[i].x = fmaf(w1, __uint_as_float(v1 << 16), acc[i].x);
        acc[i].y = fmaf(w1, __uint_as_float(v1 & 0xFFFF0000u), acc[i].y);
        acc[i].x = fmaf(w2, __uint_as_float(v2 << 16), acc[i].x);
        acc[i].y = fmaf(w2, __uint_as_float(v2 & 0xFFFF0000u), acc[i].y);
        acc[i].x = fmaf(w3, __uint_as_float(v3 << 16), acc[i].x);
        acc[i].y = fmaf(w3, __uint_as_float(v3 & 0xFFFF0000u), acc[i].y);
      }
      for (; j < c; ++j) {
        unsigned p = sorted[s0 + j];
        unsigned v = *(const unsigned*)(xb + (size_t)(p >> 16) * 128 + cc0);
        float wg = __uint_as_float(p << 16);
        acc[i].x = fmaf(wg, __uint_as_float(v << 16), acc[i].x);
        acc[i].y = fmaf(wg, __uint_as_float(v & 0xFFFF0000u), acc[i].y);
      }
    }
    __syncthreads();   // LDS reused next chunk
  }

  // writeback: wave w writes its 8 dst rows (coalesced 256B per row)
  const int d0 = b * BDST;
#pragma unroll
  for (int i = 0; i < 8; ++i) {
    int dst = d0 + w * 8 + i;
    if (dst < N) {
      unsigned p = ((unsigned)f2bf(acc[i].y) << 16) | (unsigned)f2bf(acc[i].x);
      *(unsigned*)(aggb + (size_t)dst * 128 + cc0) = p;
    }
  }
}

extern "C" void kernel_launch(void* const* d_in, const int* in_sizes, int n_in,
                              void* d_out, int out_size, void* d_ws, size_t ws_size,
                              hipStream_t stream) {
  const float* features = (const float*)d_in[0];
  const int* ei = (const int*)d_in[1];   // [2, E] int32
  const float* ew = (const float*)d_in[2];
  const float* Wp = (const float*)d_in[3];
  const float* bp = (const float*)d_in[4];
  const float* Wa = (const float*)d_in[5];
  const float* ba = (const float*)d_in[6];

  const int N = in_sizes[0] / 256;  // 50000
  const int E = in_sizes[1] / 2;    // 800000

  float* out = (float*)d_out;

  // Workspace layout (256B-aligned), ~32.2 MB:
  char* ws = (char*)d_ws;
  size_t o = 0;
  unsigned short* xb   = (unsigned short*)(ws + o); o += (size_t)N * 128 * 2;  // 12.8 MB
  o = (o + 255) & ~(size_t)255;
  unsigned short* aggb = (unsigned short*)(ws + o); o += (size_t)N * 128 * 2;  // 12.8 MB
  o = (o + 255) & ~(size_t)255;
  uint2* binned = (uint2*)(ws + o); o += (size_t)E * 8;                        // 6.4 MB
  o = (o + 255) & ~(size_t)255;
  int* bcnt  = (int*)(ws + o); o += NBKT * 4;
  o = (o + 255) & ~(size_t)255;
  int* bbase = (int*)(ws + o); o += (NBKT + 1) * 4;
  o = (o + 255) & ~(size_t)255;
  int* bcur  = (int*)(ws + o); o += NBKT * 4;
  o = (o + 255) & ~(size_t)255;
  unsigned short* WpT = (unsigned short*)(ws + o); o += (size_t)128 * 256 * 2; // 64 KB
  o = (o + 255) & ~(size_t)255;
  unsigned short* WaT = (unsigned short*)(ws + o); o += (size_t)128 * 128 * 2; // 32 KB

  const int nbkt_real = (N + BDST - 1) / BDST;  // 782
  const int nchunks = (E + 4095) / 4096;        // 196
  const int gemm_blocks = (N + 63) / 64;

  // bucket counters zeroed every call (ws never re-poisoned between replays).
  hipMemsetAsync(bcnt, 0, NBKT * sizeof(int), stream);

  // 0) W^T bf16 prep (tiny)
  prep_wt<<<(128 * 256 + 128 * 128 + 255) / 256, 256, 0, stream>>>(Wp, Wa, WpT, WaT);

  // 1) xb = bf16(features @ W_proj + b_proj)
  gemm_mfma<256, false, true, true><<<gemm_blocks, 256, 0, stream>>>(features, WpT, bp, xb, N);

  // 2) two-level binning by dst bucket (dst>>6)
  bucket_count<<<256, 256, 0, stream>>>(ei, bcnt, E);
  scan_buckets<<<1, 1024, 0, stream>>>(bcnt, bbase, bcur, E);
  bin_fill<<<nchunks, 256, 0, stream>>>(ei, ew, bcur, binned, E);

  // 3) per-bucket counting-sort + register-accumulated gather (no float atomics)
  bucket_sort_gather<<<nbkt_real, 512, 0, stream>>>(xb, binned, bbase, aggb, N);

  // 4) out = relu(aggb @ W_agg + b_agg)
  gemm_mfma<128, true, false, false><<<gemm_blocks, 256, 0, stream>>>(aggb, WaT, ba, out, N);
}

// Round 16
// 113.162 us; speedup vs baseline: 7.0276x; 1.3262x over previous
//
#include <hip/hip_runtime.h>

typedef __attribute__((ext_vector_type(8))) short bf16x8;   // 8 bf16 = 4 VGPRs
typedef __attribute__((ext_vector_type(4))) float f32x4;    // MFMA acc

#define NBKT 1024         // padded bucket array (real buckets = ceil(N/64) = 782)
#define BDST 64           // dsts per bucket
#define CHUNK 2048        // entries per sort pass in bucket_sort_gather

// fp32 -> bf16 round-to-nearest-even
__device__ __forceinline__ unsigned short f2bf(float f) {
  unsigned int u = __float_as_uint(f);
  return (unsigned short)((u + 0x7FFFu + ((u >> 16) & 1u)) >> 16);
}

// ---------------- MFMA bf16 GEMM: out[M,128] = act(A[M,K] @ W[K,128] + bias) ------
// BT[128][K] staged ONCE into LDS with XOR swizzle (byte ^= (row&7)<<4): K-loop is
// 1 global A-load + 8 conflict-free ds_read_b128 + 8 MFMA per 32-k step.
// Fragment layout (m89/m91-verified): A/B lane l -> elem row/col=l&15, k=(l>>4)*8+i;
// C/D lane l -> col=l&15, row=(l>>4)*4+j.
template<int K, bool RELU, bool OBF16, bool A_F32>
__global__ __launch_bounds__(256) void gemm_mfma(const void* __restrict__ Av,
                                                 const unsigned short* __restrict__ BT,
                                                 const float* __restrict__ bias,
                                                 void* __restrict__ outv, int M) {
  __shared__ unsigned short BTl[128 * K];   // 64KB (K=256) / 32KB (K=128)
  const int t = threadIdx.x;
  const int w = t >> 6;
  const int l = t & 63;
  const int r0 = blockIdx.x * 64 + w * 16;
  const int arow = l & 15;
  const int kq = l >> 4;

  // ---- stage BT -> LDS, swizzled writes ----
  constexpr int CPR = K / 8;            // 16B chunks per row
  constexpr int TOTAL = 128 * CPR;      // total 16B chunks (= 16*K)
  constexpr int CPT = TOTAL / 256;      // chunks per thread (K=256 -> 16, K=128 -> 8)
  static_assert(CPT * 256 == TOTAL, "staging must cover all of BTl");
#pragma unroll
  for (int c = 0; c < CPT; ++c) {
    int idx = c * 256 + t;
    int row = idx / CPR;
    int within = idx % CPR;
    unsigned swz = (unsigned)(within * 16) ^ ((unsigned)(row & 7) << 4);
    *(uint4*)((char*)BTl + (size_t)row * (K * 2) + swz) =
        *(const uint4*)(BT + (size_t)row * K + within * 8);
  }
  __syncthreads();

  int rowA = r0 + arow; if (rowA >= M) rowA = M - 1;

  f32x4 acc[8];
#pragma unroll
  for (int n = 0; n < 8; ++n) acc[n] = (f32x4){0.f, 0.f, 0.f, 0.f};

#pragma unroll
  for (int ks = 0; ks < K / 32; ++ks) {
    bf16x8 a;
    if (A_F32) {
      const float* ap = (const float*)Av + (size_t)rowA * K + ks * 32 + kq * 8;
      float4 f0 = *(const float4*)ap;
      float4 f1 = *(const float4*)(ap + 4);
      a[0] = (short)f2bf(f0.x); a[1] = (short)f2bf(f0.y);
      a[2] = (short)f2bf(f0.z); a[3] = (short)f2bf(f0.w);
      a[4] = (short)f2bf(f1.x); a[5] = (short)f2bf(f1.y);
      a[6] = (short)f2bf(f1.z); a[7] = (short)f2bf(f1.w);
    } else {
      a = *(const bf16x8*)((const unsigned short*)Av + (size_t)rowA * K + ks * 32 + kq * 8);
    }
#pragma unroll
    for (int n = 0; n < 8; ++n) {
      int rowB = n * 16 + arow;
      unsigned boff = (unsigned)(ks * 64 + kq * 16) ^ ((unsigned)(rowB & 7) << 4);
      bf16x8 b = *(const bf16x8*)((const char*)BTl + (size_t)rowB * (K * 2) + boff);
      acc[n] = __builtin_amdgcn_mfma_f32_16x16x32_bf16(a, b, acc[n], 0, 0, 0);
    }
  }

#pragma unroll
  for (int n = 0; n < 8; ++n) {
    int col = n * 16 + arow;
    float bv = bias[col];
#pragma unroll
    for (int j = 0; j < 4; ++j) {
      int row = r0 + kq * 4 + j;
      if (row < M) {
        float v = acc[n][j] + bv;
        if (RELU) v = fmaxf(v, 0.f);
        if (OBF16) ((unsigned short*)outv)[(size_t)row * 128 + col] = f2bf(v);
        else       ((float*)outv)[(size_t)row * 128 + col] = v;
      }
    }
  }
}

// ---------------- W transpose + bf16 convert (tiny, once per call) ----------------
__global__ __launch_bounds__(256) void prep_wt(const float* __restrict__ Wp,
                                               const float* __restrict__ Wa,
                                               unsigned short* __restrict__ WpT,
                                               unsigned short* __restrict__ WaT) {
  int i = blockIdx.x * 256 + threadIdx.x;
  if (i < 128 * 256) {                 // WpT[128][256] <- Wp[256][128]
    int c = i >> 8, k = i & 255;
    WpT[i] = f2bf(Wp[k * 128 + c]);
  } else if (i < 128 * 256 + 128 * 128) {
    int j = i - 128 * 256;             // WaT[128][128] <- Wa[128][128]
    int c = j >> 7, k = j & 127;
    WaT[j] = f2bf(Wa[k * 128 + c]);
  }
}

// ---------------- Pass A1: per-bucket edge counts (LDS-aggregated) ----------------
__global__ __launch_bounds__(256) void bucket_count(const int* __restrict__ ei,
                                                    int* __restrict__ bcnt, int E) {
  __shared__ int c[NBKT];
  for (int i = threadIdx.x; i < NBKT; i += 256) c[i] = 0;
  __syncthreads();
  for (int e = blockIdx.x * 256 + threadIdx.x; e < E; e += gridDim.x * 256)
    atomicAdd(&c[ei[E + e] >> 6], 1);
  __syncthreads();
  for (int i = threadIdx.x; i < NBKT; i += 256)
    if (c[i]) atomicAdd(&bcnt[i], c[i]);
}

// ---------------- Pass A2: exclusive scan of 1024 bucket counts ----------------
__global__ __launch_bounds__(1024) void scan_buckets(const int* __restrict__ bcnt,
                                                     int* __restrict__ bbase,
                                                     int* __restrict__ bcur, int E) {
  __shared__ int s[1024];
  int t = threadIdx.x;
  int v = bcnt[t];
  s[t] = v;
  __syncthreads();
#pragma unroll
  for (int o = 1; o < 1024; o <<= 1) {
    int tv = (t >= o) ? s[t - o] : 0;
    __syncthreads();
    s[t] += tv;
    __syncthreads();
  }
  int excl = s[t] - v;
  bbase[t] = excl;
  bcur[t] = excl;
  if (t == 1023) bbase[1024] = E;
}

// ---------------- Pass A3: bin edges (block-aggregated reservation) ----------------
// binned[j] = { dstLocal (0..63), (src<<16)|bf16(w) }
__global__ __launch_bounds__(256) void bin_fill(const int* __restrict__ ei,
                                                const float* __restrict__ ew,
                                                int* __restrict__ bcur,
                                                uint2* __restrict__ binned, int E) {
  __shared__ int cnt[NBKT];
  __shared__ int base[NBKT];
  const int t = threadIdx.x;
  const int c0 = blockIdx.x * 4096;
  for (int i = t; i < NBKT; i += 256) cnt[i] = 0;
  __syncthreads();

  int dst[16]; unsigned pk[16]; int rnk[16];
#pragma unroll
  for (int i = 0; i < 16; ++i) {
    int e = c0 + i * 256 + t;
    if (e < E) {
      int d = ei[E + e];
      dst[i] = d;
      pk[i] = ((unsigned)ei[e] << 16) | (unsigned)f2bf(ew[e]);
      rnk[i] = atomicAdd(&cnt[d >> 6], 1);
    } else dst[i] = -1;
  }
  __syncthreads();
  for (int i = t; i < NBKT; i += 256) {
    int c = cnt[i];
    base[i] = c ? atomicAdd(&bcur[i], c) : 0;
  }
  __syncthreads();
#pragma unroll
  for (int i = 0; i < 16; ++i) {
    if (dst[i] >= 0) {
      int b = dst[i] >> 6;
      binned[base[b] + rnk[i]] = make_uint2((unsigned)(dst[i] & 63), pk[i]);
    }
  }
}

// ---------------- Pass B: counting-sort + register-accumulate gather ----------------
// One block (512 thr) per 64-dst bucket. Sort chunk to dst-order in LDS, then wave w
// accumulates dsts [w*8, w*8+8) with 8-edge-batched gathers (8 loads in flight).
__global__ __launch_bounds__(512) void bucket_sort_gather(
    const unsigned short* __restrict__ xb,
    const uint2* __restrict__ binned,
    const int* __restrict__ bbase,
    unsigned short* __restrict__ aggb, int N) {
  __shared__ unsigned sorted[CHUNK];   // 8 KB
  __shared__ int cnt[BDST];
  __shared__ int scn[BDST];
  __shared__ int start[BDST];

  const int b = blockIdx.x;
  const int t = threadIdx.x;
  const int w = t >> 6, l = t & 63;
  const int cc0 = l * 2;
  const int js = bbase[b], je = bbase[b + 1];

  float2 acc[8];
#pragma unroll
  for (int i = 0; i < 8; ++i) acc[i] = make_float2(0.f, 0.f);

  for (int cs = js; cs < je; cs += CHUNK) {
    const int n = min(CHUNK, je - cs);
    if (t < BDST) cnt[t] = 0;
    __syncthreads();

    int dl[4]; unsigned pk[4]; int rk[4];
#pragma unroll
    for (int q = 0; q < 4; ++q) {
      int i = q * 512 + t;
      if (i < n) {
        uint2 e = binned[cs + i];
        dl[q] = (int)e.x; pk[q] = e.y;
        rk[q] = atomicAdd(&cnt[dl[q]], 1);   // native int LDS atomic
      } else dl[q] = -1;
    }
    __syncthreads();

    if (t < BDST) scn[t] = cnt[t];
    __syncthreads();
#pragma unroll
    for (int o = 1; o < BDST; o <<= 1) {
      int v = 0;
      if (t < BDST && t >= o) v = scn[t - o];
      __syncthreads();
      if (t < BDST) scn[t] += v;
      __syncthreads();
    }
    if (t < BDST) start[t] = scn[t] - cnt[t];
    __syncthreads();

#pragma unroll
    for (int q = 0; q < 4; ++q)
      if (dl[q] >= 0) sorted[start[dl[q]] + rk[q]] = pk[q];
    __syncthreads();

    // accumulate: wave w owns dl in [w*8, w*8+8); 8 gathers in flight
    for (int i = 0; i < 8; ++i) {
      const int d = w * 8 + i;
      const int s0 = start[d], c = cnt[d];   // wave-uniform LDS broadcast
      int j = 0;
      for (; j + 8 <= c; j += 8) {
        unsigned p[8], v[8];
#pragma unroll
        for (int q = 0; q < 8; ++q) p[q] = sorted[s0 + j + q];
#pragma unroll
        for (int q = 0; q < 8; ++q)
          v[q] = *(const unsigned*)(xb + (size_t)(p[q] >> 16) * 128 + cc0);
#pragma unroll
        for (int q = 0; q < 8; ++q) {
          float wg = __uint_as_float(p[q] << 16);
          acc[i].x = fmaf(wg, __uint_as_float(v[q] << 16), acc[i].x);
          acc[i].y = fmaf(wg, __uint_as_float(v[q] & 0xFFFF0000u), acc[i].y);
        }
      }
      for (; j + 4 <= c; j += 4) {
        unsigned p[4], v[4];
#pragma unroll
        for (int q = 0; q < 4; ++q) p[q] = sorted[s0 + j + q];
#pragma unroll
        for (int q = 0; q < 4; ++q)
          v[q] = *(const unsigned*)(xb + (size_t)(p[q] >> 16) * 128 + cc0);
#pragma unroll
        for (int q = 0; q < 4; ++q) {
          float wg = __uint_as_float(p[q] << 16);
          acc[i].x = fmaf(wg, __uint_as_float(v[q] << 16), acc[i].x);
          acc[i].y = fmaf(wg, __uint_as_float(v[q] & 0xFFFF0000u), acc[i].y);
        }
      }
      for (; j < c; ++j) {
        unsigned p = sorted[s0 + j];
        unsigned v = *(const unsigned*)(xb + (size_t)(p >> 16) * 128 + cc0);
        float wg = __uint_as_float(p << 16);
        acc[i].x = fmaf(wg, __uint_as_float(v << 16), acc[i].x);
        acc[i].y = fmaf(wg, __uint_as_float(v & 0xFFFF0000u), acc[i].y);
      }
    }
    __syncthreads();   // LDS reused next chunk
  }

  // writeback: wave w writes its 8 dst rows (coalesced 256B per row)
  const int d0 = b * BDST;
#pragma unroll
  for (int i = 0; i < 8; ++i) {
    int dst = d0 + w * 8 + i;
    if (dst < N) {
      unsigned p = ((unsigned)f2bf(acc[i].y) << 16) | (unsigned)f2bf(acc[i].x);
      *(unsigned*)(aggb + (size_t)dst * 128 + cc0) = p;
    }
  }
}

extern "C" void kernel_launch(void* const* d_in, const int* in_sizes, int n_in,
                              void* d_out, int out_size, void* d_ws, size_t ws_size,
                              hipStream_t stream) {
  const float* features = (const float*)d_in[0];
  const int* ei = (const int*)d_in[1];   // [2, E] int32
  const float* ew = (const float*)d_in[2];
  const float* Wp = (const float*)d_in[3];
  const float* bp = (const float*)d_in[4];
  const float* Wa = (const float*)d_in[5];
  const float* ba = (const float*)d_in[6];

  const int N = in_sizes[0] / 256;  // 50000
  const int E = in_sizes[1] / 2;    // 800000

  float* out = (float*)d_out;

  // Workspace layout (256B-aligned), ~32.2 MB:
  char* ws = (char*)d_ws;
  size_t o = 0;
  unsigned short* xb   = (unsigned short*)(ws + o); o += (size_t)N * 128 * 2;  // 12.8 MB
  o = (o + 255) & ~(size_t)255;
  unsigned short* aggb = (unsigned short*)(ws + o); o += (size_t)N * 128 * 2;  // 12.8 MB
  o = (o + 255) & ~(size_t)255;
  uint2* binned = (uint2*)(ws + o); o += (size_t)E * 8;                        // 6.4 MB
  o = (o + 255) & ~(size_t)255;
  int* bcnt  = (int*)(ws + o); o += NBKT * 4;
  o = (o + 255) & ~(size_t)255;
  int* bbase = (int*)(ws + o); o += (NBKT + 1) * 4;
  o = (o + 255) & ~(size_t)255;
  int* bcur  = (int*)(ws + o); o += NBKT * 4;
  o = (o + 255) & ~(size_t)255;
  unsigned short* WpT = (unsigned short*)(ws + o); o += (size_t)128 * 256 * 2; // 64 KB
  o = (o + 255) & ~(size_t)255;
  unsigned short* WaT = (unsigned short*)(ws + o); o += (size_t)128 * 128 * 2; // 32 KB

  const int nbkt_real = (N + BDST - 1) / BDST;  // 782
  const int nchunks = (E + 4095) / 4096;        // 196
  const int gemm_blocks = (N + 63) / 64;

  // bucket counters zeroed every call (ws never re-poisoned between replays).
  hipMemsetAsync(bcnt, 0, NBKT * sizeof(int), stream);

  // 0) W^T bf16 prep (tiny)
  prep_wt<<<(128 * 256 + 128 * 128 + 255) / 256, 256, 0, stream>>>(Wp, Wa, WpT, WaT);

  // 1) xb = bf16(features @ W_proj + b_proj)
  gemm_mfma<256, false, true, true><<<gemm_blocks, 256, 0, stream>>>(features, WpT, bp, xb, N);

  // 2) two-level binning by dst bucket (dst>>6)
  bucket_count<<<256, 256, 0, stream>>>(ei, bcnt, E);
  scan_buckets<<<1, 1024, 0, stream>>>(bcnt, bbase, bcur, E);
  bin_fill<<<nchunks, 256, 0, stream>>>(ei, ew, bcur, binned, E);

  // 3) per-bucket counting-sort + register-accumulated gather (no float atomics)
  bucket_sort_gather<<<nbkt_real, 512, 0, stream>>>(xb, binned, bbase, aggb, N);

  // 4) out = relu(aggb @ W_agg + b_agg)
  gemm_mfma<128, true, false, false><<<gemm_blocks, 256, 0, stream>>>(aggb, WaT, ba, out, N);
}